// Round 1
// 87.117 us; speedup vs baseline: 1.0040x; 1.0040x over previous
//
#include <hip/hip_runtime.h>

// x [32,512,512,1] f32, w [1,8] f32 -> y [32,512,512,1] f32.
// Reference == per-row 512-pt circular conv with real spectrum G(v)=1/|H(v)|^4,
// H(v) = sum_{j<8} w[j] e^{-2pi i v j/512}.
// Pack two rows as z = x1 + i*x2; G real => y1 = Re(ifft(G*fft(z))), y2 = Im.
// Radix-8 DIF forward (natural -> digit-reversed) + radix-8 DIT inverse
// (digit-reversed -> natural); G applied digit-reversed, 1/512 folded into G.
//
// R7 (this round):
//  (1) All block-invariant constants (G spectrum + both twiddle tables) hoisted
//      into a 1-wave setup kernel writing 9 KB to d_ws. The hot kernel had been
//      recomputing 72 quarter-rate v_sin/v_cos + 8 full-precision f32 divisions
//      + a dft8 per thread in EVERY one of 8192 blocks. Now: 16 coalesced,
//      L2-resident loads, zero trans ops, zero divisions in the hot path.
//  (2) Complex arithmetic rewritten on ext_vector float2 so the backend emits
//      packed v_pk_add_f32 / v_pk_fma_f32 (full-rate 2xf32 on CDNA4) -> the
//      ~40 complex add/subs per dft8 cost 1 VALU op instead of 2.
// Carried from R6: float2 LDS (b64), unified swizzle phi(q)=q+2(q>>6) (b64 bank
// floor, per-thread read-set==write-set per stage), single wave per block.

#define WDIM 512

typedef float v2f __attribute__((ext_vector_type(2)));

__device__ __forceinline__ v2f mkv2(float x, float y) { v2f r; r.x = x; r.y = y; return r; }

// +/- i * a
template <int SIGN> __device__ __forceinline__ v2f cmul_i(v2f a) {
    return (SIGN > 0) ? mkv2(-a.y, a.x) : mkv2(a.y, -a.x);
}
// v * (c + i s)
__device__ __forceinline__ v2f twmul(v2f v, float c, float s) {
    return v * c + cmul_i<1>(v) * s;
}

// 8-point DFT, b_t = sum_j a_j w8^{jt}, w8 = e^{SIGN*2pi i/8}.
template <int SIGN> __device__ __forceinline__ void dft8(const v2f* a, v2f* b) {
    v2f t0 = a[0] + a[4], t4 = a[0] - a[4];
    v2f t1 = a[1] + a[5], t5 = a[1] - a[5];
    v2f t2 = a[2] + a[6], t6 = cmul_i<SIGN>(a[2] - a[6]);
    v2f t3 = a[3] + a[7], t7 = cmul_i<SIGN>(a[3] - a[7]);
    v2f E0 = t0 + t2, E2 = t0 - t2;
    v2f E1 = t4 + t6, E3 = t4 - t6;
    v2f O0 = t1 + t3, O2 = t1 - t3;
    v2f O1 = t5 + t7, O3 = t5 - t7;
    const float C = 0.70710678118654752f;
    v2f O1w = twmul(O1, C, SIGN * C);     // cmul by (C, SIGN*C)
    v2f O2w = cmul_i<SIGN>(O2);
    v2f O3w = twmul(O3, -C, SIGN * C);    // cmul by (-C, SIGN*C)
    b[0] = E0 + O0;  b[4] = E0 - O0;
    b[1] = E1 + O1w; b[5] = E1 - O1w;
    b[2] = E2 + O2w; b[6] = E2 - O2w;
    b[3] = E3 + O3w; b[7] = E3 - O3w;
}

// cplx-unit LDS swizzle; injective on [0,512); max 511+14=525 -> plane 528.
__device__ __forceinline__ int phi(int q) { return q + ((q >> 6) << 1); }

// ---------------------------------------------------------------------------
// Setup kernel (1 block, 1 wave): block-invariant tables into d_ws.
// Layout (floats): [0,512)   Gdr  — digit-reversed G, 1/512 ifft scale folded
//                  [512,1408)    tw512 as float2[7][64]: (cos,sin)(u*t/512)
//                  [1408,2304)   tw64  as float2[7][64]: (cos,sin)((u&7)*t/64)
// Total 9216 B. Native v_sin/v_cos take REVOLUTIONS; args exact rationals.
// ---------------------------------------------------------------------------
__global__ void fft_conv_setup(const float* __restrict__ w, float* __restrict__ T) {
    const int u = threadIdx.x;
    v2f* t512 = (v2f*)(T + WDIM);
    v2f* t64 = t512 + 7 * 64;
#pragma unroll
    for (int t = 1; t < 8; ++t) {
        float f = (float)(u * t) * (1.0f / 512.0f);
        t512[(t - 1) * 64 + u] = mkv2(__builtin_amdgcn_cosf(f), __builtin_amdgcn_sinf(f));
        float g = (float)((u & 7) * t) * (1.0f / 64.0f);
        t64[(t - 1) * 64 + u] = mkv2(__builtin_amdgcn_cosf(g), __builtin_amdgcn_sinf(g));
    }
    // Gdr[8u+t] = G(64t+c), c = 8(u&7)+(u>>3); H(64t+c) = dft8 of twiddled taps.
    const int c = ((u & 7) << 3) | (u >> 3);
    v2f m[8], Hv[8];
    m[0] = mkv2(w[0], 0.0f);
#pragma unroll
    for (int j = 1; j < 8; ++j) {
        float f = (float)(c * j) * (1.0f / 512.0f);
        float sn = __builtin_amdgcn_sinf(f);
        float cs = __builtin_amdgcn_cosf(f);
        float wj = w[j];
        m[j] = mkv2(wj * cs, -wj * sn);
    }
    dft8<-1>(m, Hv);
    float Gv[8];
#pragma unroll
    for (int t = 0; t < 8; ++t) {
        float m2 = Hv[t].x * Hv[t].x + Hv[t].y * Hv[t].y;
        Gv[t] = (1.0f / 512.0f) / (m2 * m2);   // full-precision div: fine here, once
    }
    float4* Gp = (float4*)T;
    Gp[2 * u] = make_float4(Gv[0], Gv[1], Gv[2], Gv[3]);
    Gp[2 * u + 1] = make_float4(Gv[4], Gv[5], Gv[6], Gv[7]);
}

// ---------------------------------------------------------------------------
// One 64-thread (single-wave) block = one row-pair. Thread u owns {u + 64j}.
// [regs] fwd m=512 -> LDS -> fwd m=64 -> LDS -> fwd m=8 · G · inv m=8 ->
// LDS -> inv m=64 -> LDS -> inv m=512 [regs] -> global.
// ---------------------------------------------------------------------------
__global__ __launch_bounds__(64, 4) void fft_conv_kernel(const float* __restrict__ x,
                                                         const float* __restrict__ T,
                                                         float* __restrict__ y) {
    __shared__ v2f l[528];
    const int u = threadIdx.x;
    const int pair = blockIdx.x;
    const float* x1 = x + (size_t)(2 * pair) * WDIM;
    const float* x2 = x1 + WDIM;

    v2f a[8], b[8];
#pragma unroll
    for (int j = 0; j < 8; ++j) {
        int i = u + 64 * j;
        a[j] = mkv2(x1[i], x2[i]);
    }

    // Block-invariant tables: 16 coalesced loads, L2/L3-resident (9 KB shared
    // by all 8192 blocks). Issued while the x loads are in flight.
    v2f tw5[7], tw6[7];
    const v2f* t512 = (const v2f*)(T + WDIM);
    const v2f* t64 = t512 + 7 * 64;
#pragma unroll
    for (int t = 0; t < 7; ++t) {
        tw5[t] = t512[t * 64 + u];
        tw6[t] = t64[t * 64 + u];
    }
    const float4* Gp = (const float4*)T;
    float4 g0 = Gp[2 * u];
    float4 g1 = Gp[2 * u + 1];

    const int base = ((u >> 3) << 6) | (u & 7);

    // ---- forward DIF, m=512 (regs -> LDS) ----
    dft8<-1>(a, b);
#pragma unroll
    for (int t = 1; t < 8; ++t) b[t] = twmul(b[t], tw5[t - 1].x, -tw5[t - 1].y);
#pragma unroll
    for (int t = 0; t < 8; ++t) l[phi(u + 64 * t)] = b[t];
    __syncthreads();

    // ---- forward DIF, m=64 (in-place slot set per thread) ----
#pragma unroll
    for (int j = 0; j < 8; ++j) a[j] = l[phi(base + 8 * j)];
    dft8<-1>(a, b);
#pragma unroll
    for (int t = 1; t < 8; ++t) b[t] = twmul(b[t], tw6[t - 1].x, -tw6[t - 1].y);
#pragma unroll
    for (int t = 0; t < 8; ++t) l[phi(base + 8 * t)] = b[t];
    __syncthreads();

    // ---- fwd m=8 · G · inv m=8 (in-place slot set per thread) ----
    {
        const int cb = 8 * u;
#pragma unroll
        for (int j = 0; j < 8; ++j) a[j] = l[phi(cb + j)];
        dft8<-1>(a, b);
        b[0] *= g0.x; b[1] *= g0.y; b[2] *= g0.z; b[3] *= g0.w;
        b[4] *= g1.x; b[5] *= g1.y; b[6] *= g1.z; b[7] *= g1.w;
        dft8<1>(b, a);
#pragma unroll
        for (int j = 0; j < 8; ++j) l[phi(cb + j)] = a[j];
    }
    __syncthreads();

    // ---- inverse DIT, m=64 (twiddle BEFORE butterfly; in-place slots) ----
#pragma unroll
    for (int t = 0; t < 8; ++t) a[t] = l[phi(base + 8 * t)];
#pragma unroll
    for (int t = 1; t < 8; ++t) a[t] = twmul(a[t], tw6[t - 1].x, tw6[t - 1].y);
    dft8<1>(a, b);
#pragma unroll
    for (int j = 0; j < 8; ++j) l[phi(base + 8 * j)] = b[j];
    __syncthreads();

    // ---- inverse DIT, m=512 (LDS -> regs -> global) ----
#pragma unroll
    for (int t = 0; t < 8; ++t) a[t] = l[phi(u + 64 * t)];
#pragma unroll
    for (int t = 1; t < 8; ++t) a[t] = twmul(a[t], tw5[t - 1].x, tw5[t - 1].y);
    dft8<1>(a, b);
    float* y1 = y + (size_t)(2 * pair) * WDIM;
    float* y2 = y1 + WDIM;
#pragma unroll
    for (int j = 0; j < 8; ++j) {
        int i = u + 64 * j;
        y1[i] = b[j].x;
        y2[i] = b[j].y;
    }
}

extern "C" void kernel_launch(void* const* d_in, const int* in_sizes, int n_in,
                              void* d_out, int out_size, void* d_ws, size_t ws_size,
                              hipStream_t stream) {
    const float* x = (const float*)d_in[0];  // [32,512,512,1]
    const float* w = (const float*)d_in[1];  // [1,8]
    float* y = (float*)d_out;
    float* T = (float*)d_ws;                 // needs 9216 B (<< ws_size)

    // Stream order guarantees setup's writes are visible to the main kernel
    // (implicit release/acquire at dispatch boundaries spans XCD L2s).
    fft_conv_setup<<<dim3(1), dim3(64), 0, stream>>>(w, T);
    fft_conv_kernel<<<dim3(8192), dim3(64), 0, stream>>>(x, T, y);
}